// Round 2
// baseline (1248.803 us; speedup 1.0000x reference)
//
#include <hip/hip_runtime.h>
#include <hip/hip_fp16.h>

#define HID 14
#define RNODE 256      // nodes per scan-tile / bucket (fallback)
#define MAXK 512
#define PTILE 2048     // edges per partition block
#define ANODE 64       // nodes per acc block (fast path)

static __device__ inline unsigned pack2(float a, float b) {
    return __builtin_bit_cast(unsigned, __floats2half2_rn(a, b));
}
static __device__ inline float2 unpack2(unsigned u) {
    return __half22float2(__builtin_bit_cast(__half2, u));
}

// two non-negative fp16 values -> 16.16 fixed point packed in u64
// (relu output => no sign, no cross-carry; integer sums are order-invariant)
static __device__ inline unsigned long long fx2(unsigned packed) {
    float2 f = unpack2(packed);
    unsigned lo = (unsigned)__builtin_fmaf(f.x, 65536.0f, 0.5f);
    unsigned hi = (unsigned)__builtin_fmaf(f.y, 65536.0f, 0.5f);
    return ((unsigned long long)hi << 32) | (unsigned long long)lo;
}

// ============ Fast path: node-exact sort infra ============

// per-node histogram via global atomics (6.4M adds over 100k counters)
__global__ __launch_bounds__(256) void histn_kernel(
    const int* __restrict__ col, int E, int* __restrict__ hist)
{
    for (int i = blockIdx.x * 256 + threadIdx.x; i < E; i += gridDim.x * 256)
        atomicAdd(&hist[col[i]], 1);
}

// stage A: per-256-tile exclusive scan + tile sums
__global__ __launch_bounds__(256) void scan_a_kernel(
    const int* __restrict__ hist, int* __restrict__ excl,
    int* __restrict__ bsum, int N)
{
    __shared__ int s[256];
    int t = threadIdx.x;
    int g = blockIdx.x * 256 + t;
    int v = (g < N) ? hist[g] : 0;
    s[t] = v;
    __syncthreads();
    for (int off = 1; off < 256; off <<= 1) {
        int add = (t >= off) ? s[t - off] : 0;
        __syncthreads();
        s[t] += add;
        __syncthreads();
    }
    if (g < N) excl[g] = s[t] - v;
    if (t == 255) bsum[blockIdx.x] = s[255];
}

// stage B: single-block exclusive scan of tile sums (K <= 512)
__global__ __launch_bounds__(512) void scan_b_kernel(
    const int* __restrict__ bsum, int* __restrict__ boff, int K)
{
    __shared__ int s[512];
    int t = threadIdx.x;
    int v = (t < K) ? bsum[t] : 0;
    s[t] = v;
    __syncthreads();
    for (int off = 1; off < 512; off <<= 1) {
        int add = (t >= off) ? s[t - off] : 0;
        __syncthreads();
        s[t] += add;
        __syncthreads();
    }
    if (t < K) boff[t] = s[t] - v;
}

// stage C: combine -> start[], cursor[]
__global__ __launch_bounds__(256) void scan_c_kernel(
    const int* __restrict__ excl, const int* __restrict__ boff,
    int* __restrict__ start, int* __restrict__ cursor, int N)
{
    for (int g = blockIdx.x * 256 + threadIdx.x; g < N; g += gridDim.x * 256) {
        int v = excl[g] + boff[g >> 8];
        start[g] = v;
        cursor[g] = v;
    }
}

// ============ Fast path: partition + MLP1 (node-exact positions) ============
// No barriers, no LDS hist. Cursor atomics + x gathers issued early so their
// latency hides under the MLP of the 8-edge tile. (256,4): allow ~128 VGPR.
__global__ __launch_bounds__(256, 4) void part_kernel(
    const float* __restrict__ x,
    const int* __restrict__ ei, int E,
    const float* __restrict__ ea,
    const float* __restrict__ w1a, const float* __restrict__ b1a,
    int* __restrict__ cursor, uint4* __restrict__ recs)
{
    __shared__ float s_w1a[15 * HID];
    __shared__ float s_b1a[HID];
    for (int i = threadIdx.x; i < 15 * HID; i += 256) s_w1a[i] = w1a[i];
    if (threadIdx.x < HID) s_b1a[threadIdx.x] = b1a[threadIdx.x];
    __syncthreads();

    int tile0 = blockIdx.x * PTILE;
    int c[8], pos[8];
    float4 xv[8];
#pragma unroll
    for (int k = 0; k < 8; ++k) {
        int idx = tile0 + k * 256 + threadIdx.x;
        if (idx < E) {
            int r = ei[idx];
            c[k] = ei[E + idx];
            pos[k] = atomicAdd(&cursor[c[k]], 1);
            xv[k] = ((const float4*)x)[r];
        }
    }

#pragma unroll
    for (int k = 0; k < 8; ++k) {
        int idx = tile0 + k * 256 + threadIdx.x;
        if (idx < E) {
            float4 q = xv[k];
            float mn = q.y * q.y + q.z * q.z + q.w * q.w - q.x * q.x;

            float v[HID];
            const float2* ep = (const float2*)(ea + (size_t)idx * HID);
#pragma unroll
            for (int p = 0; p < 7; ++p) {
                float2 t = ep[p];
                v[2 * p] = t.x;
                v[2 * p + 1] = t.y;
            }

            float h1[HID];
#pragma unroll
            for (int j = 0; j < HID; ++j) h1[j] = s_b1a[j] + mn * s_w1a[j];
#pragma unroll
            for (int p = 0; p < HID; ++p) {
                float vp = v[p];
#pragma unroll
                for (int j = 0; j < HID; ++j) h1[j] += vp * s_w1a[(p + 1) * HID + j];
            }
#pragma unroll
            for (int j = 0; j < HID; ++j) h1[j] = fmaxf(h1[j], 0.0f);

            size_t ps = (size_t)pos[k];
            uint4 ua, ub;
            ua.x = pack2(h1[0], h1[1]);   ua.y = pack2(h1[2], h1[3]);
            ua.z = pack2(h1[4], h1[5]);   ua.w = pack2(h1[6], h1[7]);
            ub.x = pack2(h1[8], h1[9]);   ub.y = pack2(h1[10], h1[11]);
            ub.z = pack2(h1[12], h1[13]); ub.w = (unsigned)c[k];
            recs[2 * ps]     = ua;
            recs[2 * ps + 1] = ub;
        }
    }
}

// ============ Fast path: atomic-free accumulate ============
// Records are node-contiguous. One wave per node: 64 lanes read coalesced,
// accumulate 7 packed u64 fixed-point partials, butterfly shfl_xor reduce.
__global__ __launch_bounds__(256) void acc_kernel(
    const uint4* __restrict__ recs,
    const int* __restrict__ start, const int* __restrict__ hist,
    float* __restrict__ part, int N)
{
    __shared__ float sres[ANODE * 16];
    int wave = threadIdx.x >> 6;
    int lane = threadIdx.x & 63;
    int nbase = blockIdx.x * ANODE;

    for (int q = wave; q < ANODE; q += 4) {
        int node = nbase + q;
        if (node < N) {
            int s0 = start[node];
            int cb = hist[node];
            unsigned long long p0 = 0, p1 = 0, p2 = 0, p3 = 0, p4 = 0, p5 = 0, p6 = 0;
            for (int base = 0; base < cb; base += 64) {
                int i = base + lane;
                if (i < cb) {
                    size_t ri = (size_t)(s0 + i);
                    uint4 ua = recs[2 * ri];
                    uint4 ub = recs[2 * ri + 1];
                    p0 += fx2(ua.x); p1 += fx2(ua.y); p2 += fx2(ua.z);
                    p3 += fx2(ua.w); p4 += fx2(ub.x); p5 += fx2(ub.y);
                    p6 += fx2(ub.z);
                }
            }
#pragma unroll
            for (int off = 32; off >= 1; off >>= 1) {
                p0 += __shfl_xor(p0, off);
                p1 += __shfl_xor(p1, off);
                p2 += __shfl_xor(p2, off);
                p3 += __shfl_xor(p3, off);
                p4 += __shfl_xor(p4, off);
                p5 += __shfl_xor(p5, off);
                p6 += __shfl_xor(p6, off);
            }
            if (lane == 0) {
                float* d = &sres[q * 16];
                const float sc = 1.0f / 65536.0f;
                d[0]  = (float)(unsigned)p0 * sc;  d[1]  = (float)(unsigned)(p0 >> 32) * sc;
                d[2]  = (float)(unsigned)p1 * sc;  d[3]  = (float)(unsigned)(p1 >> 32) * sc;
                d[4]  = (float)(unsigned)p2 * sc;  d[5]  = (float)(unsigned)(p2 >> 32) * sc;
                d[6]  = (float)(unsigned)p3 * sc;  d[7]  = (float)(unsigned)(p3 >> 32) * sc;
                d[8]  = (float)(unsigned)p4 * sc;  d[9]  = (float)(unsigned)(p4 >> 32) * sc;
                d[10] = (float)(unsigned)p5 * sc;  d[11] = (float)(unsigned)(p5 >> 32) * sc;
                d[12] = (float)(unsigned)p6 * sc;  d[13] = (float)(unsigned)(p6 >> 32) * sc;
                d[14] = (float)cb;
                d[15] = 0.0f;
            }
        }
    }
    __syncthreads();

    // cooperative coalesced write: 256 float4s
    int i = threadIdx.x;
    int node = nbase + (i >> 2);
    if (node < N)
        ((float4*)part)[(size_t)node * 4 + (i & 3)] = ((const float4*)sres)[i];
}

// ============ Fast path: node MLP2 (single partial slice) ============
__global__ __launch_bounds__(256) void node2_kernel(
    const float* __restrict__ x,
    const float* __restrict__ part,
    const float* __restrict__ w1b, const float* __restrict__ b1b,
    const float* __restrict__ w2a, const float* __restrict__ b2a,
    const float* __restrict__ w2b, const float* __restrict__ b2b,
    float* __restrict__ out, int N)
{
    __shared__ float s_w1b[HID * HID], s_b1b[HID];
    __shared__ float s_w2a[15 * HID], s_b2a[HID];
    __shared__ float s_w2b[HID * HID], s_b2b[HID];
    for (int i = threadIdx.x; i < HID * HID; i += 256) {
        s_w1b[i] = w1b[i];
        s_w2b[i] = w2b[i];
    }
    for (int i = threadIdx.x; i < 15 * HID; i += 256) s_w2a[i] = w2a[i];
    if (threadIdx.x < HID) {
        s_b1b[threadIdx.x] = b1b[threadIdx.x];
        s_b2a[threadIdx.x] = b2a[threadIdx.x];
        s_b2b[threadIdx.x] = b2b[threadIdx.x];
    }
    __syncthreads();

    int n = blockIdx.x * 256 + threadIdx.x;
    if (n >= N) return;

    float s[15];
    {
        const float4* p = (const float4*)(part + (size_t)n * 16);
        float4 a = p[0], bq = p[1], cq = p[2], dq = p[3];
        s[0] = a.x;  s[1] = a.y;  s[2] = a.z;  s[3] = a.w;
        s[4] = bq.x; s[5] = bq.y; s[6] = bq.z; s[7] = bq.w;
        s[8] = cq.x; s[9] = cq.y; s[10] = cq.z; s[11] = cq.w;
        s[12] = dq.x; s[13] = dq.y; s[14] = dq.z;   // dq.w = pad
    }

    float cntf = s[14];
    float gate = (cntf >= 0.5f) ? 1.0f : 0.0f;      // ref: mean==0 if no edges
    float inv = gate / fmaxf(cntf, 1.0f);

    // mean(h2) = W1b . mean(relu_h1) + b1b   (gated; W1b folded by linearity)
    float mh[HID];
#pragma unroll
    for (int j = 0; j < HID; ++j) mh[j] = gate * s_b1b[j];
#pragma unroll
    for (int k = 0; k < HID; ++k) {
        float rk = s[k] * inv;
#pragma unroll
        for (int j = 0; j < HID; ++j) mh[j] += rk * s_w1b[k * HID + j];
    }

    float4 xv = ((const float4*)x)[n];
    float mn = xv.y * xv.y + xv.z * xv.z + xv.w * xv.w - xv.x * xv.x;

    float h1[HID];
#pragma unroll
    for (int j = 0; j < HID; ++j) h1[j] = s_b2a[j] + mn * s_w2a[j];
#pragma unroll
    for (int k = 0; k < HID; ++k) {
        float vk = mh[k];
#pragma unroll
        for (int j = 0; j < HID; ++j) h1[j] += vk * s_w2a[(k + 1) * HID + j];
    }
#pragma unroll
    for (int j = 0; j < HID; ++j) h1[j] = fmaxf(h1[j], 0.0f);

    float h2[HID];
#pragma unroll
    for (int j = 0; j < HID; ++j) h2[j] = s_b2b[j];
#pragma unroll
    for (int k = 0; k < HID; ++k) {
        float hk = h1[k];
#pragma unroll
        for (int j = 0; j < HID; ++j) h2[j] += hk * s_w2b[k * HID + j];
    }

    float2* op = (float2*)(out + (size_t)n * HID);
#pragma unroll
    for (int k = 0; k < 7; ++k) {
        float2 t; t.x = h2[2 * k]; t.y = h2[2 * k + 1];
        op[k] = t;
    }
}

// ============ Fallback A: bucket bins + MLP in acc ============

__global__ __launch_bounds__(256) void hist_kernel(
    const int* __restrict__ col, int E, int* __restrict__ hist, int K)
{
    __shared__ int sh[MAXK];
    for (int i = threadIdx.x; i < K; i += 256) sh[i] = 0;
    __syncthreads();
    for (int i = blockIdx.x * 256 + threadIdx.x; i < E; i += gridDim.x * 256)
        atomicAdd(&sh[col[i] >> 8], 1);
    __syncthreads();
    for (int i = threadIdx.x; i < K; i += 256)
        if (sh[i]) atomicAdd(&hist[i], sh[i]);
}

__global__ __launch_bounds__(512) void scan_kernel(
    const int* __restrict__ hist,
    int* __restrict__ start, int* __restrict__ cursor, int K)
{
    __shared__ int s[512];
    int t = threadIdx.x;
    int v = (t < K) ? hist[t] : 0;
    s[t] = v;
    __syncthreads();
    for (int off = 1; off < 512; off <<= 1) {
        int add = (t >= off) ? s[t - off] : 0;
        __syncthreads();
        s[t] += add;
        __syncthreads();
    }
    if (t < K) {
        int ex = s[t] - v;
        start[t] = ex;
        cursor[t] = ex;
    }
}

__global__ __launch_bounds__(256) void r2_part_kernel(
    const int* __restrict__ ei, int E,
    int* __restrict__ cursor, int4* __restrict__ bins, int K)
{
    __shared__ int sh[MAXK];
    __shared__ int sbase[MAXK];
    for (int i = threadIdx.x; i < K; i += 256) sh[i] = 0;
    __syncthreads();
    int tile0 = blockIdx.x * PTILE;
    int e[8], r[8], c[8], rk[8];
#pragma unroll
    for (int k = 0; k < 8; ++k) {
        int idx = tile0 + k * 256 + threadIdx.x;
        e[k] = idx;
        if (idx < E) {
            r[k] = ei[idx];
            c[k] = ei[E + idx];
            rk[k] = atomicAdd(&sh[c[k] >> 8], 1);
        }
    }
    __syncthreads();
    for (int i = threadIdx.x; i < K; i += 256)
        sbase[i] = sh[i] ? atomicAdd(&cursor[i], sh[i]) : 0;
    __syncthreads();
#pragma unroll
    for (int k = 0; k < 8; ++k) {
        if (e[k] < E) {
            int pos = sbase[c[k] >> 8] + rk[k];
            int4 t; t.x = e[k]; t.y = r[k]; t.z = c[k]; t.w = 0;
            bins[pos] = t;
        }
    }
}

__global__ __launch_bounds__(256) void r2_acc_kernel(
    const float* __restrict__ x, const float* __restrict__ ea,
    const int4* __restrict__ bins,
    const int* __restrict__ start, const int* __restrict__ hist,
    const float* __restrict__ w1a, const float* __restrict__ b1a,
    const float* __restrict__ w1b, const float* __restrict__ b1b,
    float* __restrict__ part, int N)
{
    __shared__ float sacc[RNODE * 15];
    __shared__ float s_w1a[15 * HID], s_b1a[HID];
    __shared__ float s_w1b[HID * HID], s_b1b[HID];
    for (int i = threadIdx.x; i < 15 * HID; i += 256) s_w1a[i] = w1a[i];
    for (int i = threadIdx.x; i < HID * HID; i += 256) s_w1b[i] = w1b[i];
    if (threadIdx.x < HID) { s_b1a[threadIdx.x] = b1a[threadIdx.x]; s_b1b[threadIdx.x] = b1b[threadIdx.x]; }
    for (int i = threadIdx.x; i < RNODE * 15; i += 256) sacc[i] = 0.0f;
    __syncthreads();

    int b = blockIdx.x / 2, m = blockIdx.x % 2;
    int s0 = start[b], cb = hist[b];
    int lo = s0 + (int)((long long)cb * m / 2);
    int hi = s0 + (int)((long long)cb * (m + 1) / 2);
    int nbase = b << 8;

    for (int i = lo + threadIdx.x; i < hi; i += 256) {
        int4 t = bins[i];
        float4 xv = ((const float4*)x)[t.y];
        float mn = xv.y * xv.y + xv.z * xv.z + xv.w * xv.w - xv.x * xv.x;
        float v[HID];
        const float2* ep = (const float2*)(ea + (size_t)t.x * HID);
#pragma unroll
        for (int k = 0; k < 7; ++k) { float2 u2 = ep[k]; v[2*k] = u2.x; v[2*k+1] = u2.y; }
        float h1[HID];
#pragma unroll
        for (int j = 0; j < HID; ++j) h1[j] = s_b1a[j] + mn * s_w1a[j];
#pragma unroll
        for (int k = 0; k < HID; ++k) {
            float vk = v[k];
#pragma unroll
            for (int j = 0; j < HID; ++j) h1[j] += vk * s_w1a[(k + 1) * HID + j];
        }
#pragma unroll
        for (int j = 0; j < HID; ++j) h1[j] = fmaxf(h1[j], 0.0f);
        float h2[HID];
#pragma unroll
        for (int j = 0; j < HID; ++j) h2[j] = s_b1b[j];
#pragma unroll
        for (int k = 0; k < HID; ++k) {
            float hk = h1[k];
#pragma unroll
            for (int j = 0; j < HID; ++j) h2[j] += hk * s_w1b[k * HID + j];
        }
        float* dst = &sacc[(t.z - nbase) * 15];
#pragma unroll
        for (int j = 0; j < HID; ++j) atomicAdd(dst + j, h2[j]);
        atomicAdd(dst + HID, 1.0f);
    }
    __syncthreads();
    for (int i = threadIdx.x; i < RNODE * 15; i += 256) {
        int node = nbase + i / 15;
        if (node < N) part[((size_t)m * N + node) * 15 + (i % 15)] = sacc[i];
    }
}

__global__ __launch_bounds__(256) void r2_node2_kernel(
    const float* __restrict__ x, const float* __restrict__ part,
    const float* __restrict__ w2a, const float* __restrict__ b2a,
    const float* __restrict__ w2b, const float* __restrict__ b2b,
    float* __restrict__ out, int N)
{
    __shared__ float s_w2a[15 * HID], s_b2a[HID];
    __shared__ float s_w2b[HID * HID], s_b2b[HID];
    for (int i = threadIdx.x; i < 15 * HID; i += 256) s_w2a[i] = w2a[i];
    for (int i = threadIdx.x; i < HID * HID; i += 256) s_w2b[i] = w2b[i];
    if (threadIdx.x < HID) { s_b2a[threadIdx.x] = b2a[threadIdx.x]; s_b2b[threadIdx.x] = b2b[threadIdx.x]; }
    __syncthreads();
    int n = blockIdx.x * 256 + threadIdx.x;
    if (n >= N) return;
    float4 xv = ((const float4*)x)[n];
    float mn = xv.y * xv.y + xv.z * xv.z + xv.w * xv.w - xv.x * xv.x;
    float s[15];
#pragma unroll
    for (int j = 0; j < 15; ++j)
        s[j] = part[(size_t)n * 15 + j] + part[((size_t)N + n) * 15 + j];
    float inv = 1.0f / fmaxf(s[HID], 1.0f);
    float h1[HID];
#pragma unroll
    for (int j = 0; j < HID; ++j) h1[j] = s_b2a[j] + mn * s_w2a[j];
#pragma unroll
    for (int k = 0; k < HID; ++k) {
        float vk = s[k] * inv;
#pragma unroll
        for (int j = 0; j < HID; ++j) h1[j] += vk * s_w2a[(k + 1) * HID + j];
    }
#pragma unroll
    for (int j = 0; j < HID; ++j) h1[j] = fmaxf(h1[j], 0.0f);
    float h2[HID];
#pragma unroll
    for (int j = 0; j < HID; ++j) h2[j] = s_b2b[j];
#pragma unroll
    for (int k = 0; k < HID; ++k) {
        float hk = h1[k];
#pragma unroll
        for (int j = 0; j < HID; ++j) h2[j] += hk * s_w2b[k * HID + j];
    }
    float2* op = (float2*)(out + (size_t)n * HID);
#pragma unroll
    for (int k = 0; k < 7; ++k) { float2 t; t.x = h2[2*k]; t.y = h2[2*k+1]; op[k] = t; }
}

// ============ Fallback B: global atomics ============

__global__ __launch_bounds__(256) void edge_kernel(
    const float* __restrict__ x, const int* __restrict__ ei,
    const float* __restrict__ ea,
    const float* __restrict__ w1a, const float* __restrict__ b1a,
    const float* __restrict__ w1b, const float* __restrict__ b1b,
    float* __restrict__ seg, float* __restrict__ cnt, int E)
{
    __shared__ float s_w1a[15 * HID], s_b1a[HID];
    __shared__ float s_w1b[HID * HID], s_b1b[HID];
    for (int i = threadIdx.x; i < 15 * HID; i += 256) s_w1a[i] = w1a[i];
    for (int i = threadIdx.x; i < HID * HID; i += 256) s_w1b[i] = w1b[i];
    if (threadIdx.x < HID) { s_b1a[threadIdx.x] = b1a[threadIdx.x]; s_b1b[threadIdx.x] = b1b[threadIdx.x]; }
    __syncthreads();
    int e = blockIdx.x * 256 + threadIdx.x;
    if (e >= E) return;
    int r = ei[e], c = ei[E + e];
    float4 xv = ((const float4*)x)[r];
    float mn = xv.y * xv.y + xv.z * xv.z + xv.w * xv.w - xv.x * xv.x;
    float v[HID];
    const float2* ep = (const float2*)(ea + (size_t)e * HID);
#pragma unroll
    for (int k = 0; k < 7; ++k) { float2 t = ep[k]; v[2*k] = t.x; v[2*k+1] = t.y; }
    float h1[HID];
#pragma unroll
    for (int j = 0; j < HID; ++j) h1[j] = s_b1a[j] + mn * s_w1a[j];
#pragma unroll
    for (int k = 0; k < HID; ++k) {
        float vk = v[k];
#pragma unroll
        for (int j = 0; j < HID; ++j) h1[j] += vk * s_w1a[(k + 1) * HID + j];
    }
#pragma unroll
    for (int j = 0; j < HID; ++j) h1[j] = fmaxf(h1[j], 0.0f);
    float h2[HID];
#pragma unroll
    for (int j = 0; j < HID; ++j) h2[j] = s_b1b[j];
#pragma unroll
    for (int k = 0; k < HID; ++k) {
        float hk = h1[k];
#pragma unroll
        for (int j = 0; j < HID; ++j) h2[j] += hk * s_w1b[k * HID + j];
    }
    float* dst = seg + (size_t)c * HID;
#pragma unroll
    for (int j = 0; j < HID; ++j) unsafeAtomicAdd(dst + j, h2[j]);
    unsafeAtomicAdd(cnt + c, 1.0f);
}

__global__ __launch_bounds__(256) void node_kernel(
    const float* __restrict__ x, const float* __restrict__ seg,
    const float* __restrict__ cnt,
    const float* __restrict__ w2a, const float* __restrict__ b2a,
    const float* __restrict__ w2b, const float* __restrict__ b2b,
    float* __restrict__ out, int N)
{
    __shared__ float s_w2a[15 * HID], s_b2a[HID];
    __shared__ float s_w2b[HID * HID], s_b2b[HID];
    for (int i = threadIdx.x; i < 15 * HID; i += 256) s_w2a[i] = w2a[i];
    for (int i = threadIdx.x; i < HID * HID; i += 256) s_w2b[i] = w2b[i];
    if (threadIdx.x < HID) { s_b2a[threadIdx.x] = b2a[threadIdx.x]; s_b2b[threadIdx.x] = b2b[threadIdx.x]; }
    __syncthreads();
    int n = blockIdx.x * 256 + threadIdx.x;
    if (n >= N) return;
    float4 xv = ((const float4*)x)[n];
    float mn = xv.y * xv.y + xv.z * xv.z + xv.w * xv.w - xv.x * xv.x;
    float inv = 1.0f / fmaxf(cnt[n], 1.0f);
    float v[HID];
    const float2* sp = (const float2*)(seg + (size_t)n * HID);
#pragma unroll
    for (int k = 0; k < 7; ++k) { float2 t = sp[k]; v[2*k] = t.x*inv; v[2*k+1] = t.y*inv; }
    float h1[HID];
#pragma unroll
    for (int j = 0; j < HID; ++j) h1[j] = s_b2a[j] + mn * s_w2a[j];
#pragma unroll
    for (int k = 0; k < HID; ++k) {
        float vk = v[k];
#pragma unroll
        for (int j = 0; j < HID; ++j) h1[j] += vk * s_w2a[(k + 1) * HID + j];
    }
#pragma unroll
    for (int j = 0; j < HID; ++j) h1[j] = fmaxf(h1[j], 0.0f);
    float h2[HID];
#pragma unroll
    for (int j = 0; j < HID; ++j) h2[j] = s_b2b[j];
#pragma unroll
    for (int k = 0; k < HID; ++k) {
        float hk = h1[k];
#pragma unroll
        for (int j = 0; j < HID; ++j) h2[j] += hk * s_w2b[k * HID + j];
    }
    float2* op = (float2*)(out + (size_t)n * HID);
#pragma unroll
    for (int k = 0; k < 7; ++k) { float2 t; t.x = h2[2*k]; t.y = h2[2*k+1]; op[k] = t; }
}

// ============ Launch ============

extern "C" void kernel_launch(void* const* d_in, const int* in_sizes, int n_in,
                              void* d_out, int out_size, void* d_ws, size_t ws_size,
                              hipStream_t stream)
{
    const float* x   = (const float*)d_in[0];
    const int*   ei  = (const int*)d_in[1];
    const float* ea  = (const float*)d_in[2];
    const float* w1a = (const float*)d_in[5];
    const float* b1a = (const float*)d_in[6];
    const float* w1b = (const float*)d_in[7];
    const float* b1b = (const float*)d_in[8];
    const float* w2a = (const float*)d_in[9];
    const float* b2a = (const float*)d_in[10];
    const float* w2b = (const float*)d_in[11];
    const float* b2b = (const float*)d_in[12];

    const int N = in_sizes[0] / 4;   // 100000
    const int E = in_sizes[1] / 2;   // 6400000
    const int K = (N + RNODE - 1) / RNODE;   // scan tiles (must be <= MAXK)

    size_t recs_bytes = (size_t)E * 32;
    size_t part_bytes = (size_t)N * 16 * sizeof(float);
    size_t nint       = ((size_t)N * sizeof(int) + 255) & ~(size_t)255;
    size_t need_fast  = recs_bytes + part_bytes + 4 * nint
                      + 2 * MAXK * sizeof(int) + 256;

    size_t bins_bytes   = (size_t)E * sizeof(int4);
    size_t r2part_bytes = (size_t)2 * N * 15 * sizeof(float);
    size_t ints_bytes   = (size_t)3 * MAXK * sizeof(int);
    size_t need_r2      = bins_bytes + r2part_bytes + ints_bytes + 256;

    if (K <= MAXK && ws_size >= need_fast) {
        char*  base    = (char*)d_ws;
        uint4* recs    = (uint4*)base;                         base += recs_bytes;
        float* part    = (float*)base;                         base += part_bytes;
        int*   hist_n  = (int*)base;                           base += nint;
        int*   start_n = (int*)base;                           base += nint;
        int*   cursor  = (int*)base;                           base += nint;
        int*   excl    = (int*)base;                           base += nint;
        int*   bsum    = (int*)base;                           base += MAXK * sizeof(int);
        int*   boff    = (int*)base;

        hipMemsetAsync(hist_n, 0, (size_t)N * sizeof(int), stream);
        histn_kernel<<<2048, 256, 0, stream>>>(ei + E, E, hist_n);
        scan_a_kernel<<<K, 256, 0, stream>>>(hist_n, excl, bsum, N);
        scan_b_kernel<<<1, 512, 0, stream>>>(bsum, boff, K);
        int cbks = (N + 256 * 8 - 1) / (256 * 8);
        scan_c_kernel<<<cbks, 256, 0, stream>>>(excl, boff, start_n, cursor, N);
        int pb = (E + PTILE - 1) / PTILE;
        part_kernel<<<pb, 256, 0, stream>>>(x, ei, E, ea, w1a, b1a, cursor, recs);
        int ab = (N + ANODE - 1) / ANODE;
        acc_kernel<<<ab, 256, 0, stream>>>(recs, start_n, hist_n, part, N);
        int nb = (N + 255) / 256;
        node2_kernel<<<nb, 256, 0, stream>>>(x, part, w1b, b1b, w2a, b2a, w2b, b2b,
                                             (float*)d_out, N);
    } else if (K <= MAXK && ws_size >= need_r2) {
        int4*  bins   = (int4*)d_ws;
        float* part   = (float*)((char*)d_ws + bins_bytes);
        int*   hist   = (int*)((char*)d_ws + bins_bytes + r2part_bytes);
        int*   cursor = hist + MAXK;
        int*   start  = cursor + MAXK;

        hipMemsetAsync(hist, 0, (size_t)K * sizeof(int), stream);
        hist_kernel<<<1024, 256, 0, stream>>>(ei + E, E, hist, K);
        scan_kernel<<<1, 512, 0, stream>>>(hist, start, cursor, K);
        int pb = (E + PTILE - 1) / PTILE;
        r2_part_kernel<<<pb, 256, 0, stream>>>(ei, E, cursor, bins, K);
        r2_acc_kernel<<<K * 2, 256, 0, stream>>>(x, ea, bins, start, hist,
                                                 w1a, b1a, w1b, b1b, part, N);
        int nb = (N + 255) / 256;
        r2_node2_kernel<<<nb, 256, 0, stream>>>(x, part, w2a, b2a, w2b, b2b,
                                                (float*)d_out, N);
    } else {
        float* seg = (float*)d_ws;
        float* cnt = seg + (size_t)N * HID;
        hipMemsetAsync(d_ws, 0, (size_t)N * (HID + 1) * sizeof(float), stream);
        int eb = (E + 255) / 256;
        edge_kernel<<<eb, 256, 0, stream>>>(x, ei, ea, w1a, b1a, w1b, b1b, seg, cnt, E);
        int nb = (N + 255) / 256;
        node_kernel<<<nb, 256, 0, stream>>>(x, seg, cnt, w2a, b2a, w2b, b2b,
                                            (float*)d_out, N);
    }
}

// Round 3
// 910.285 us; speedup vs baseline: 1.3719x; 1.3719x over previous
//
#include <hip/hip_runtime.h>
#include <hip/hip_fp16.h>

#define HID 14
#define RNODE 256      // nodes per bucket
#define MSLICE 4       // acc slices per bucket (fast path)
#define MAXK 512
#define PTILE 2048     // edges per partition block
#define CHK 512        // edges per staged ea chunk (28672 B LDS)

static __device__ inline unsigned pack2(float a, float b) {
    return __builtin_bit_cast(unsigned, __floats2half2_rn(a, b));
}
static __device__ inline float2 unpack2(unsigned u) {
    return __half22float2(__builtin_bit_cast(__half2, u));
}

// two non-negative fp16 values -> 16.16 fixed point packed in u64
static __device__ inline unsigned long long fx2(unsigned packed) {
    float2 f = unpack2(packed);
    unsigned lo = (unsigned)__builtin_fmaf(f.x, 65536.0f, 0.5f);
    unsigned hi = (unsigned)__builtin_fmaf(f.y, 65536.0f, 0.5f);
    return ((unsigned long long)hi << 32) | (unsigned long long)lo;
}

// async global->LDS 16B (coalesced staging). LDS dest = wave-uniform base + lane*16.
static __device__ inline void g2lds16(const void* g, void* l) {
    __builtin_amdgcn_global_load_lds(
        (const __attribute__((address_space(1))) unsigned int*)g,
        (__attribute__((address_space(3))) unsigned int*)l, 16, 0, 0);
}

// ============ Shared infra: hist + scan ============

__global__ __launch_bounds__(256) void hist_kernel(
    const int* __restrict__ col, int E, int* __restrict__ hist, int K)
{
    __shared__ int sh[MAXK];
    for (int i = threadIdx.x; i < K; i += 256) sh[i] = 0;
    __syncthreads();
    for (int i = blockIdx.x * 256 + threadIdx.x; i < E; i += gridDim.x * 256)
        atomicAdd(&sh[col[i] >> 8], 1);
    __syncthreads();
    for (int i = threadIdx.x; i < K; i += 256)
        if (sh[i]) atomicAdd(&hist[i], sh[i]);
}

__global__ __launch_bounds__(512) void scan_kernel(
    const int* __restrict__ hist,
    int* __restrict__ start, int* __restrict__ cursor, int K)
{
    __shared__ int s[512];
    int t = threadIdx.x;
    int v = (t < K) ? hist[t] : 0;
    s[t] = v;
    __syncthreads();
    for (int off = 1; off < 512; off <<= 1) {
        int add = (t >= off) ? s[t - off] : 0;
        __syncthreads();
        s[t] += add;
        __syncthreads();
    }
    if (t < K) {
        int ex = s[t] - v;
        start[t] = ex;
        cursor[t] = ex;
    }
}

// ============ Fast path ============

// K3: partition + MLP1 fused, ea staged through LDS (coalesced global_load_lds).
__global__ __launch_bounds__(256) void part_kernel(
    const float* __restrict__ x,
    const int* __restrict__ ei, int E,
    const float* __restrict__ ea,
    const float* __restrict__ w1a, const float* __restrict__ b1a,
    int* __restrict__ cursor, uint4* __restrict__ recs, int K)
{
    __shared__ int sh[MAXK];
    __shared__ int sbase[MAXK];
    __shared__ float s_w1a[15 * HID];
    __shared__ float s_b1a[HID];
    __shared__ __align__(16) float sea[CHK * HID];   // 28672 B
    for (int i = threadIdx.x; i < 15 * HID; i += 256) s_w1a[i] = w1a[i];
    if (threadIdx.x < HID) s_b1a[threadIdx.x] = b1a[threadIdx.x];
    for (int i = threadIdx.x; i < K; i += 256) sh[i] = 0;
    __syncthreads();

    int t = threadIdx.x;
    int tile0 = blockIdx.x * PTILE;
    int r[8], c[8], rk[8];
#pragma unroll
    for (int k = 0; k < 8; ++k) {
        int idx = tile0 + k * 256 + t;
        if (idx < E) {
            r[k] = ei[idx];
            c[k] = ei[E + idx];
            rk[k] = atomicAdd(&sh[c[k] >> 8], 1);
        }
    }
    __syncthreads();
    for (int i = t; i < K; i += 256)
        sbase[i] = sh[i] ? atomicAdd(&cursor[i], sh[i]) : 0;
    // sbase visibility covered by the first __syncthreads in the chunk loop

    if (tile0 + PTILE <= E) {
        int wave = t >> 6, lane = t & 63;
#pragma unroll 1
        for (int ch = 0; ch < PTILE / CHK; ++ch) {
            // stage 512 edges' ea rows: 28672 B = 28 x 1KB units, 7 per wave
            const char* gsrc = (const char*)ea + (size_t)(tile0 + ch * CHK) * 56;
#pragma unroll
            for (int u = 0; u < 7; ++u) {
                int inst = wave * 7 + u;
                g2lds16(gsrc + inst * 1024 + lane * 16, (char*)sea + inst * 1024);
            }
            asm volatile("s_waitcnt vmcnt(0)" ::: "memory");
            __syncthreads();

#pragma unroll
            for (int e2 = 0; e2 < 2; ++e2) {
                int le = e2 * 256 + t;       // edge within chunk
                int k = ch * 2 + e2;         // matches phase-1 arrays
                float4 q = ((const float4*)x)[r[k]];
                float mn = q.y * q.y + q.z * q.z + q.w * q.w - q.x * q.x;

                float v[HID];
                const float2* ep = (const float2*)((const char*)sea + (size_t)le * 56);
#pragma unroll
                for (int p = 0; p < 7; ++p) {
                    float2 tv = ep[p];
                    v[2 * p] = tv.x;
                    v[2 * p + 1] = tv.y;
                }

                float h1[HID];
#pragma unroll
                for (int j = 0; j < HID; ++j) h1[j] = s_b1a[j] + mn * s_w1a[j];
#pragma unroll
                for (int p = 0; p < HID; ++p) {
                    float vp = v[p];
#pragma unroll
                    for (int j = 0; j < HID; ++j) h1[j] += vp * s_w1a[(p + 1) * HID + j];
                }
#pragma unroll
                for (int j = 0; j < HID; ++j) h1[j] = fmaxf(h1[j], 0.0f);

                size_t ps = (size_t)(sbase[c[k] >> 8] + rk[k]);
                uint4 ua, ub;
                ua.x = pack2(h1[0], h1[1]);   ua.y = pack2(h1[2], h1[3]);
                ua.z = pack2(h1[4], h1[5]);   ua.w = pack2(h1[6], h1[7]);
                ub.x = pack2(h1[8], h1[9]);   ub.y = pack2(h1[10], h1[11]);
                ub.z = pack2(h1[12], h1[13]); ub.w = (unsigned)c[k];
                recs[2 * ps]     = ua;
                recs[2 * ps + 1] = ub;
            }
            __syncthreads();   // before next stage overwrites sea
        }
    } else {
        // partial tile: direct guarded loads (rare/cold)
        __syncthreads();
#pragma unroll
        for (int k = 0; k < 8; ++k) {
            int idx = tile0 + k * 256 + t;
            if (idx < E) {
                float4 q = ((const float4*)x)[r[k]];
                float mn = q.y * q.y + q.z * q.z + q.w * q.w - q.x * q.x;
                float v[HID];
                const float2* ep = (const float2*)(ea + (size_t)idx * HID);
#pragma unroll
                for (int p = 0; p < 7; ++p) {
                    float2 tv = ep[p];
                    v[2 * p] = tv.x;
                    v[2 * p + 1] = tv.y;
                }
                float h1[HID];
#pragma unroll
                for (int j = 0; j < HID; ++j) h1[j] = s_b1a[j] + mn * s_w1a[j];
#pragma unroll
                for (int p = 0; p < HID; ++p) {
                    float vp = v[p];
#pragma unroll
                    for (int j = 0; j < HID; ++j) h1[j] += vp * s_w1a[(p + 1) * HID + j];
                }
#pragma unroll
                for (int j = 0; j < HID; ++j) h1[j] = fmaxf(h1[j], 0.0f);
                size_t ps = (size_t)(sbase[c[k] >> 8] + rk[k]);
                uint4 ua, ub;
                ua.x = pack2(h1[0], h1[1]);   ua.y = pack2(h1[2], h1[3]);
                ua.z = pack2(h1[4], h1[5]);   ua.w = pack2(h1[6], h1[7]);
                ub.x = pack2(h1[8], h1[9]);   ub.y = pack2(h1[10], h1[11]);
                ub.z = pack2(h1[12], h1[13]); ub.w = (unsigned)c[k];
                recs[2 * ps]     = ua;
                recs[2 * ps + 1] = ub;
            }
        }
    }
}

// K4: streaming accumulate, 7 u64 LDS atomics per record.
// u64 #0: f0[0:28) + f1[28:56) (16 frac bits each) + count[56:64).
// u64 #1..6: feature pairs as 32/32 16.16 fixed. Lane-serial law: ~36.6us/atomic.
static __device__ inline void acc_rec7(const uint4* __restrict__ recs, size_t i,
                                       unsigned long long* __restrict__ sacc,
                                       int nbase)
{
    uint4 ua = recs[2 * i];
    uint4 ub = recs[2 * i + 1];
    unsigned long long* dst = &sacc[(size_t)(((int)ub.w - nbase) * 7)];
    float2 f = unpack2(ua.x);
    unsigned long long a0 =
          (unsigned long long)(unsigned)__builtin_fmaf(f.x, 65536.0f, 0.5f)
        | ((unsigned long long)(unsigned)__builtin_fmaf(f.y, 65536.0f, 0.5f) << 28)
        | (1ULL << 56);
    atomicAdd(&dst[0], a0);
    atomicAdd(&dst[1], fx2(ua.y));
    atomicAdd(&dst[2], fx2(ua.z));
    atomicAdd(&dst[3], fx2(ua.w));
    atomicAdd(&dst[4], fx2(ub.x));
    atomicAdd(&dst[5], fx2(ub.y));
    atomicAdd(&dst[6], fx2(ub.z));
}

__global__ __launch_bounds__(256) void acc_kernel(
    const uint4* __restrict__ recs,
    const int* __restrict__ start, const int* __restrict__ hist,
    float* __restrict__ part, int N)
{
    __shared__ unsigned long long sacc[RNODE * 7];   // 14336 B
    for (int i = threadIdx.x; i < RNODE * 7; i += 256) sacc[i] = 0ULL;
    __syncthreads();

    int b = blockIdx.x / MSLICE;
    int m = blockIdx.x % MSLICE;
    int s0 = start[b], cb = hist[b];
    int lo = s0 + (int)((long long)cb * m / MSLICE);
    int hi = s0 + (int)((long long)cb * (m + 1) / MSLICE);
    int nbase = b << 8;

    int i = lo + threadIdx.x;
    for (; i < hi - 256; i += 512) {
        acc_rec7(recs, (size_t)i, sacc, nbase);
        acc_rec7(recs, (size_t)(i + 256), sacc, nbase);
    }
    if (i < hi) acc_rec7(recs, (size_t)i, sacc, nbase);
    __syncthreads();

    // epilogue: one thread per node
    int t = threadIdx.x;
    int node = nbase + t;
    if (node < N) {
        const unsigned long long* p = &sacc[t * 7];
        const float sc = 1.0f / 65536.0f;
        unsigned long long p0 = p[0];
        float v[14];
        v[0] = (float)(unsigned)(p0 & 0xFFFFFFFULL) * sc;
        v[1] = (float)(unsigned)((p0 >> 28) & 0xFFFFFFFULL) * sc;
        float cnt = (float)(unsigned)(p0 >> 56);
#pragma unroll
        for (int k = 1; k < 7; ++k) {
            unsigned long long w = p[k];
            v[2 * k]     = (float)(unsigned)w         * sc;
            v[2 * k + 1] = (float)(unsigned)(w >> 32) * sc;
        }
        float4* q = (float4*)(part + ((size_t)m * N + node) * 16);
        float4 o;
        o.x = v[0];  o.y = v[1];  o.z = v[2];  o.w = v[3];  q[0] = o;
        o.x = v[4];  o.y = v[5];  o.z = v[6];  o.w = v[7];  q[1] = o;
        o.x = v[8];  o.y = v[9];  o.z = v[10]; o.w = v[11]; q[2] = o;
        o.x = v[12]; o.y = v[13]; o.z = cnt;   o.w = 0.0f;  q[3] = o;
    }
}

// K5: merge partials, mean, fold W1b/b1b (linearity), MLP2 -> out
__global__ __launch_bounds__(256) void node2_kernel(
    const float* __restrict__ x,
    const float* __restrict__ part,
    const float* __restrict__ w1b, const float* __restrict__ b1b,
    const float* __restrict__ w2a, const float* __restrict__ b2a,
    const float* __restrict__ w2b, const float* __restrict__ b2b,
    float* __restrict__ out, int N)
{
    __shared__ float s_w1b[HID * HID], s_b1b[HID];
    __shared__ float s_w2a[15 * HID], s_b2a[HID];
    __shared__ float s_w2b[HID * HID], s_b2b[HID];
    for (int i = threadIdx.x; i < HID * HID; i += 256) {
        s_w1b[i] = w1b[i];
        s_w2b[i] = w2b[i];
    }
    for (int i = threadIdx.x; i < 15 * HID; i += 256) s_w2a[i] = w2a[i];
    if (threadIdx.x < HID) {
        s_b1b[threadIdx.x] = b1b[threadIdx.x];
        s_b2a[threadIdx.x] = b2a[threadIdx.x];
        s_b2b[threadIdx.x] = b2b[threadIdx.x];
    }
    __syncthreads();

    int n = blockIdx.x * 256 + threadIdx.x;
    if (n >= N) return;

    float s[15];
    {
        const float4* p = (const float4*)(part + (size_t)n * 16);
        float4 a = p[0], bq = p[1], cq = p[2], dq = p[3];
        s[0] = a.x;  s[1] = a.y;  s[2] = a.z;  s[3] = a.w;
        s[4] = bq.x; s[5] = bq.y; s[6] = bq.z; s[7] = bq.w;
        s[8] = cq.x; s[9] = cq.y; s[10] = cq.z; s[11] = cq.w;
        s[12] = dq.x; s[13] = dq.y; s[14] = dq.z;
    }
#pragma unroll
    for (int m = 1; m < MSLICE; ++m) {
        const float4* p = (const float4*)(part + ((size_t)m * N + n) * 16);
        float4 a = p[0], bq = p[1], cq = p[2], dq = p[3];
        s[0] += a.x;  s[1] += a.y;  s[2] += a.z;  s[3] += a.w;
        s[4] += bq.x; s[5] += bq.y; s[6] += bq.z; s[7] += bq.w;
        s[8] += cq.x; s[9] += cq.y; s[10] += cq.z; s[11] += cq.w;
        s[12] += dq.x; s[13] += dq.y; s[14] += dq.z;
    }

    float cntf = s[14];
    float gate = (cntf >= 0.5f) ? 1.0f : 0.0f;
    float inv = gate / fmaxf(cntf, 1.0f);

    float mh[HID];
#pragma unroll
    for (int j = 0; j < HID; ++j) mh[j] = gate * s_b1b[j];
#pragma unroll
    for (int k = 0; k < HID; ++k) {
        float rk = s[k] * inv;
#pragma unroll
        for (int j = 0; j < HID; ++j) mh[j] += rk * s_w1b[k * HID + j];
    }

    float4 xv = ((const float4*)x)[n];
    float mn = xv.y * xv.y + xv.z * xv.z + xv.w * xv.w - xv.x * xv.x;

    float h1[HID];
#pragma unroll
    for (int j = 0; j < HID; ++j) h1[j] = s_b2a[j] + mn * s_w2a[j];
#pragma unroll
    for (int k = 0; k < HID; ++k) {
        float vk = mh[k];
#pragma unroll
        for (int j = 0; j < HID; ++j) h1[j] += vk * s_w2a[(k + 1) * HID + j];
    }
#pragma unroll
    for (int j = 0; j < HID; ++j) h1[j] = fmaxf(h1[j], 0.0f);

    float h2[HID];
#pragma unroll
    for (int j = 0; j < HID; ++j) h2[j] = s_b2b[j];
#pragma unroll
    for (int k = 0; k < HID; ++k) {
        float hk = h1[k];
#pragma unroll
        for (int j = 0; j < HID; ++j) h2[j] += hk * s_w2b[k * HID + j];
    }

    float2* op = (float2*)(out + (size_t)n * HID);
#pragma unroll
    for (int k = 0; k < 7; ++k) {
        float2 t; t.x = h2[2 * k]; t.y = h2[2 * k + 1];
        op[k] = t;
    }
}

// ============ Fallback A: edge-id bins + MLP in acc ============

__global__ __launch_bounds__(256) void r2_part_kernel(
    const int* __restrict__ ei, int E,
    int* __restrict__ cursor, int4* __restrict__ bins, int K)
{
    __shared__ int sh[MAXK];
    __shared__ int sbase[MAXK];
    for (int i = threadIdx.x; i < K; i += 256) sh[i] = 0;
    __syncthreads();
    int tile0 = blockIdx.x * PTILE;
    int e[8], r[8], c[8], rk[8];
#pragma unroll
    for (int k = 0; k < 8; ++k) {
        int idx = tile0 + k * 256 + threadIdx.x;
        e[k] = idx;
        if (idx < E) {
            r[k] = ei[idx];
            c[k] = ei[E + idx];
            rk[k] = atomicAdd(&sh[c[k] >> 8], 1);
        }
    }
    __syncthreads();
    for (int i = threadIdx.x; i < K; i += 256)
        sbase[i] = sh[i] ? atomicAdd(&cursor[i], sh[i]) : 0;
    __syncthreads();
#pragma unroll
    for (int k = 0; k < 8; ++k) {
        if (e[k] < E) {
            int pos = sbase[c[k] >> 8] + rk[k];
            int4 t; t.x = e[k]; t.y = r[k]; t.z = c[k]; t.w = 0;
            bins[pos] = t;
        }
    }
}

__global__ __launch_bounds__(256) void r2_acc_kernel(
    const float* __restrict__ x, const float* __restrict__ ea,
    const int4* __restrict__ bins,
    const int* __restrict__ start, const int* __restrict__ hist,
    const float* __restrict__ w1a, const float* __restrict__ b1a,
    const float* __restrict__ w1b, const float* __restrict__ b1b,
    float* __restrict__ part, int N)
{
    __shared__ float sacc[RNODE * 15];
    __shared__ float s_w1a[15 * HID], s_b1a[HID];
    __shared__ float s_w1b[HID * HID], s_b1b[HID];
    for (int i = threadIdx.x; i < 15 * HID; i += 256) s_w1a[i] = w1a[i];
    for (int i = threadIdx.x; i < HID * HID; i += 256) s_w1b[i] = w1b[i];
    if (threadIdx.x < HID) { s_b1a[threadIdx.x] = b1a[threadIdx.x]; s_b1b[threadIdx.x] = b1b[threadIdx.x]; }
    for (int i = threadIdx.x; i < RNODE * 15; i += 256) sacc[i] = 0.0f;
    __syncthreads();

    int b = blockIdx.x / 2, m = blockIdx.x % 2;
    int s0 = start[b], cb = hist[b];
    int lo = s0 + (int)((long long)cb * m / 2);
    int hi = s0 + (int)((long long)cb * (m + 1) / 2);
    int nbase = b << 8;

    for (int i = lo + threadIdx.x; i < hi; i += 256) {
        int4 t = bins[i];
        float4 xv = ((const float4*)x)[t.y];
        float mn = xv.y * xv.y + xv.z * xv.z + xv.w * xv.w - xv.x * xv.x;
        float v[HID];
        const float2* ep = (const float2*)(ea + (size_t)t.x * HID);
#pragma unroll
        for (int k = 0; k < 7; ++k) { float2 u2 = ep[k]; v[2*k] = u2.x; v[2*k+1] = u2.y; }
        float h1[HID];
#pragma unroll
        for (int j = 0; j < HID; ++j) h1[j] = s_b1a[j] + mn * s_w1a[j];
#pragma unroll
        for (int k = 0; k < HID; ++k) {
            float vk = v[k];
#pragma unroll
            for (int j = 0; j < HID; ++j) h1[j] += vk * s_w1a[(k + 1) * HID + j];
        }
#pragma unroll
        for (int j = 0; j < HID; ++j) h1[j] = fmaxf(h1[j], 0.0f);
        float h2[HID];
#pragma unroll
        for (int j = 0; j < HID; ++j) h2[j] = s_b1b[j];
#pragma unroll
        for (int k = 0; k < HID; ++k) {
            float hk = h1[k];
#pragma unroll
            for (int j = 0; j < HID; ++j) h2[j] += hk * s_w1b[k * HID + j];
        }
        float* dst = &sacc[(t.z - nbase) * 15];
#pragma unroll
        for (int j = 0; j < HID; ++j) atomicAdd(dst + j, h2[j]);
        atomicAdd(dst + HID, 1.0f);
    }
    __syncthreads();
    for (int i = threadIdx.x; i < RNODE * 15; i += 256) {
        int node = nbase + i / 15;
        if (node < N) part[((size_t)m * N + node) * 15 + (i % 15)] = sacc[i];
    }
}

__global__ __launch_bounds__(256) void r2_node2_kernel(
    const float* __restrict__ x, const float* __restrict__ part,
    const float* __restrict__ w2a, const float* __restrict__ b2a,
    const float* __restrict__ w2b, const float* __restrict__ b2b,
    float* __restrict__ out, int N)
{
    __shared__ float s_w2a[15 * HID], s_b2a[HID];
    __shared__ float s_w2b[HID * HID], s_b2b[HID];
    for (int i = threadIdx.x; i < 15 * HID; i += 256) s_w2a[i] = w2a[i];
    for (int i = threadIdx.x; i < HID * HID; i += 256) s_w2b[i] = w2b[i];
    if (threadIdx.x < HID) { s_b2a[threadIdx.x] = b2a[threadIdx.x]; s_b2b[threadIdx.x] = b2b[threadIdx.x]; }
    __syncthreads();
    int n = blockIdx.x * 256 + threadIdx.x;
    if (n >= N) return;
    float4 xv = ((const float4*)x)[n];
    float mn = xv.y * xv.y + xv.z * xv.z + xv.w * xv.w - xv.x * xv.x;
    float s[15];
#pragma unroll
    for (int j = 0; j < 15; ++j)
        s[j] = part[(size_t)n * 15 + j] + part[((size_t)N + n) * 15 + j];
    float inv = 1.0f / fmaxf(s[HID], 1.0f);
    float h1[HID];
#pragma unroll
    for (int j = 0; j < HID; ++j) h1[j] = s_b2a[j] + mn * s_w2a[j];
#pragma unroll
    for (int k = 0; k < HID; ++k) {
        float vk = s[k] * inv;
#pragma unroll
        for (int j = 0; j < HID; ++j) h1[j] += vk * s_w2a[(k + 1) * HID + j];
    }
#pragma unroll
    for (int j = 0; j < HID; ++j) h1[j] = fmaxf(h1[j], 0.0f);
    float h2[HID];
#pragma unroll
    for (int j = 0; j < HID; ++j) h2[j] = s_b2b[j];
#pragma unroll
    for (int k = 0; k < HID; ++k) {
        float hk = h1[k];
#pragma unroll
        for (int j = 0; j < HID; ++j) h2[j] += hk * s_w2b[k * HID + j];
    }
    float2* op = (float2*)(out + (size_t)n * HID);
#pragma unroll
    for (int k = 0; k < 7; ++k) { float2 t; t.x = h2[2*k]; t.y = h2[2*k+1]; op[k] = t; }
}

// ============ Fallback B: global atomics ============

__global__ __launch_bounds__(256) void edge_kernel(
    const float* __restrict__ x, const int* __restrict__ ei,
    const float* __restrict__ ea,
    const float* __restrict__ w1a, const float* __restrict__ b1a,
    const float* __restrict__ w1b, const float* __restrict__ b1b,
    float* __restrict__ seg, float* __restrict__ cnt, int E)
{
    __shared__ float s_w1a[15 * HID], s_b1a[HID];
    __shared__ float s_w1b[HID * HID], s_b1b[HID];
    for (int i = threadIdx.x; i < 15 * HID; i += 256) s_w1a[i] = w1a[i];
    for (int i = threadIdx.x; i < HID * HID; i += 256) s_w1b[i] = w1b[i];
    if (threadIdx.x < HID) { s_b1a[threadIdx.x] = b1a[threadIdx.x]; s_b1b[threadIdx.x] = b1b[threadIdx.x]; }
    __syncthreads();
    int e = blockIdx.x * 256 + threadIdx.x;
    if (e >= E) return;
    int r = ei[e], c = ei[E + e];
    float4 xv = ((const float4*)x)[r];
    float mn = xv.y * xv.y + xv.z * xv.z + xv.w * xv.w - xv.x * xv.x;
    float v[HID];
    const float2* ep = (const float2*)(ea + (size_t)e * HID);
#pragma unroll
    for (int k = 0; k < 7; ++k) { float2 t = ep[k]; v[2*k] = t.x; v[2*k+1] = t.y; }
    float h1[HID];
#pragma unroll
    for (int j = 0; j < HID; ++j) h1[j] = s_b1a[j] + mn * s_w1a[j];
#pragma unroll
    for (int k = 0; k < HID; ++k) {
        float vk = v[k];
#pragma unroll
        for (int j = 0; j < HID; ++j) h1[j] += vk * s_w1a[(k + 1) * HID + j];
    }
#pragma unroll
    for (int j = 0; j < HID; ++j) h1[j] = fmaxf(h1[j], 0.0f);
    float h2[HID];
#pragma unroll
    for (int j = 0; j < HID; ++j) h2[j] = s_b1b[j];
#pragma unroll
    for (int k = 0; k < HID; ++k) {
        float hk = h1[k];
#pragma unroll
        for (int j = 0; j < HID; ++j) h2[j] += hk * s_w1b[k * HID + j];
    }
    float* dst = seg + (size_t)c * HID;
#pragma unroll
    for (int j = 0; j < HID; ++j) unsafeAtomicAdd(dst + j, h2[j]);
    unsafeAtomicAdd(cnt + c, 1.0f);
}

__global__ __launch_bounds__(256) void node_kernel(
    const float* __restrict__ x, const float* __restrict__ seg,
    const float* __restrict__ cnt,
    const float* __restrict__ w2a, const float* __restrict__ b2a,
    const float* __restrict__ w2b, const float* __restrict__ b2b,
    float* __restrict__ out, int N)
{
    __shared__ float s_w2a[15 * HID], s_b2a[HID];
    __shared__ float s_w2b[HID * HID], s_b2b[HID];
    for (int i = threadIdx.x; i < 15 * HID; i += 256) s_w2a[i] = w2a[i];
    for (int i = threadIdx.x; i < HID * HID; i += 256) s_w2b[i] = w2b[i];
    if (threadIdx.x < HID) { s_b2a[threadIdx.x] = b2a[threadIdx.x]; s_b2b[threadIdx.x] = b2b[threadIdx.x]; }
    __syncthreads();
    int n = blockIdx.x * 256 + threadIdx.x;
    if (n >= N) return;
    float4 xv = ((const float4*)x)[n];
    float mn = xv.y * xv.y + xv.z * xv.z + xv.w * xv.w - xv.x * xv.x;
    float inv = 1.0f / fmaxf(cnt[n], 1.0f);
    float v[HID];
    const float2* sp = (const float2*)(seg + (size_t)n * HID);
#pragma unroll
    for (int k = 0; k < 7; ++k) { float2 t = sp[k]; v[2*k] = t.x*inv; v[2*k+1] = t.y*inv; }
    float h1[HID];
#pragma unroll
    for (int j = 0; j < HID; ++j) h1[j] = s_b2a[j] + mn * s_w2a[j];
#pragma unroll
    for (int k = 0; k < HID; ++k) {
        float vk = v[k];
#pragma unroll
        for (int j = 0; j < HID; ++j) h1[j] += vk * s_w2a[(k + 1) * HID + j];
    }
#pragma unroll
    for (int j = 0; j < HID; ++j) h1[j] = fmaxf(h1[j], 0.0f);
    float h2[HID];
#pragma unroll
    for (int j = 0; j < HID; ++j) h2[j] = s_b2b[j];
#pragma unroll
    for (int k = 0; k < HID; ++k) {
        float hk = h1[k];
#pragma unroll
        for (int j = 0; j < HID; ++j) h2[j] += hk * s_w2b[k * HID + j];
    }
    float2* op = (float2*)(out + (size_t)n * HID);
#pragma unroll
    for (int k = 0; k < 7; ++k) { float2 t; t.x = h2[2*k]; t.y = h2[2*k+1]; op[k] = t; }
}

// ============ Launch ============

extern "C" void kernel_launch(void* const* d_in, const int* in_sizes, int n_in,
                              void* d_out, int out_size, void* d_ws, size_t ws_size,
                              hipStream_t stream)
{
    const float* x   = (const float*)d_in[0];
    const int*   ei  = (const int*)d_in[1];
    const float* ea  = (const float*)d_in[2];
    const float* w1a = (const float*)d_in[5];
    const float* b1a = (const float*)d_in[6];
    const float* w1b = (const float*)d_in[7];
    const float* b1b = (const float*)d_in[8];
    const float* w2a = (const float*)d_in[9];
    const float* b2a = (const float*)d_in[10];
    const float* w2b = (const float*)d_in[11];
    const float* b2b = (const float*)d_in[12];

    const int N = in_sizes[0] / 4;   // 100000
    const int E = in_sizes[1] / 2;   // 6400000
    const int K = (N + RNODE - 1) / RNODE;

    size_t recs_bytes = (size_t)E * 32;
    size_t part_bytes = (size_t)MSLICE * N * 16 * sizeof(float);
    size_t ints_bytes = (size_t)3 * MAXK * sizeof(int);
    size_t need_fast = recs_bytes + part_bytes + ints_bytes + 256;

    size_t bins_bytes = (size_t)E * sizeof(int4);
    size_t r2part_bytes = (size_t)2 * N * 15 * sizeof(float);
    size_t need_r2 = bins_bytes + r2part_bytes + ints_bytes + 256;

    if (K <= MAXK && ws_size >= need_fast) {
        uint4* recs   = (uint4*)d_ws;
        float* part   = (float*)((char*)d_ws + recs_bytes);
        int*   hist   = (int*)((char*)d_ws + recs_bytes + part_bytes);
        int*   cursor = hist + MAXK;
        int*   start  = cursor + MAXK;

        hipMemsetAsync(hist, 0, (size_t)K * sizeof(int), stream);
        hist_kernel<<<1024, 256, 0, stream>>>(ei + E, E, hist, K);
        scan_kernel<<<1, 512, 0, stream>>>(hist, start, cursor, K);
        int pb = (E + PTILE - 1) / PTILE;
        part_kernel<<<pb, 256, 0, stream>>>(x, ei, E, ea, w1a, b1a, cursor, recs, K);
        acc_kernel<<<K * MSLICE, 256, 0, stream>>>(recs, start, hist, part, N);
        int nb = (N + 255) / 256;
        node2_kernel<<<nb, 256, 0, stream>>>(x, part, w1b, b1b, w2a, b2a, w2b, b2b,
                                             (float*)d_out, N);
    } else if (K <= MAXK && ws_size >= need_r2) {
        int4*  bins   = (int4*)d_ws;
        float* part   = (float*)((char*)d_ws + bins_bytes);
        int*   hist   = (int*)((char*)d_ws + bins_bytes + r2part_bytes);
        int*   cursor = hist + MAXK;
        int*   start  = cursor + MAXK;

        hipMemsetAsync(hist, 0, (size_t)K * sizeof(int), stream);
        hist_kernel<<<1024, 256, 0, stream>>>(ei + E, E, hist, K);
        scan_kernel<<<1, 512, 0, stream>>>(hist, start, cursor, K);
        int pb = (E + PTILE - 1) / PTILE;
        r2_part_kernel<<<pb, 256, 0, stream>>>(ei, E, cursor, bins, K);
        r2_acc_kernel<<<K * 2, 256, 0, stream>>>(x, ea, bins, start, hist,
                                                 w1a, b1a, w1b, b1b, part, N);
        int nb = (N + 255) / 256;
        r2_node2_kernel<<<nb, 256, 0, stream>>>(x, part, w2a, b2a, w2b, b2b,
                                                (float*)d_out, N);
    } else {
        float* seg = (float*)d_ws;
        float* cnt = seg + (size_t)N * HID;
        hipMemsetAsync(d_ws, 0, (size_t)N * (HID + 1) * sizeof(float), stream);
        int eb = (E + 255) / 256;
        edge_kernel<<<eb, 256, 0, stream>>>(x, ei, ea, w1a, b1a, w1b, b1b, seg, cnt, E);
        int nb = (N + 255) / 256;
        node_kernel<<<nb, 256, 0, stream>>>(x, seg, cnt, w2a, b2a, w2b, b2b,
                                            (float*)d_out, N);
    }
}

// Round 4
// 771.937 us; speedup vs baseline: 1.6178x; 1.1792x over previous
//
#include <hip/hip_runtime.h>
#include <hip/hip_fp16.h>

#define HID 14
#define RNODE 256      // nodes per bucket
#define MSLICE 4       // acc slices per bucket (fast path)
#define MAXK 512
#define PTILE 2048     // edges per partition block

static __device__ inline unsigned pack2(float a, float b) {
    return __builtin_bit_cast(unsigned, __floats2half2_rn(a, b));
}
static __device__ inline float2 unpack2(unsigned u) {
    return __half22float2(__builtin_bit_cast(__half2, u));
}

// two non-negative fp16 values -> 16.16 fixed point packed in u64
static __device__ inline unsigned long long fx2(unsigned packed) {
    float2 f = unpack2(packed);
    unsigned lo = (unsigned)__builtin_fmaf(f.x, 65536.0f, 0.5f);
    unsigned hi = (unsigned)__builtin_fmaf(f.y, 65536.0f, 0.5f);
    return ((unsigned long long)hi << 32) | (unsigned long long)lo;
}

// ============ Shared infra: hist + scan ============

__global__ __launch_bounds__(256) void hist_kernel(
    const int* __restrict__ col, int E, int* __restrict__ hist, int K)
{
    __shared__ int sh[MAXK];
    for (int i = threadIdx.x; i < K; i += 256) sh[i] = 0;
    __syncthreads();
    for (int i = blockIdx.x * 256 + threadIdx.x; i < E; i += gridDim.x * 256)
        atomicAdd(&sh[col[i] >> 8], 1);
    __syncthreads();
    for (int i = threadIdx.x; i < K; i += 256)
        if (sh[i]) atomicAdd(&hist[i], sh[i]);
}

__global__ __launch_bounds__(512) void scan_kernel(
    const int* __restrict__ hist,
    int* __restrict__ start, int* __restrict__ cursor, int K)
{
    __shared__ int s[512];
    int t = threadIdx.x;
    int v = (t < K) ? hist[t] : 0;
    s[t] = v;
    __syncthreads();
    for (int off = 1; off < 512; off <<= 1) {
        int add = (t >= off) ? s[t - off] : 0;
        __syncthreads();
        s[t] += add;
        __syncthreads();
    }
    if (t < K) {
        int ex = s[t] - v;
        start[t] = ex;
        cursor[t] = ex;
    }
}

// ============ Fast path ============

static __device__ inline void mlp1_store(
    const float* __restrict__ v, float mn,
    const float* s_w1a, const float* s_b1a,
    int c, int pos, uint4* __restrict__ recs)
{
    float h1[HID];
#pragma unroll
    for (int j = 0; j < HID; ++j) h1[j] = s_b1a[j] + mn * s_w1a[j];
#pragma unroll
    for (int p = 0; p < HID; ++p) {
        float vp = v[p];
#pragma unroll
        for (int j = 0; j < HID; ++j) h1[j] += vp * s_w1a[(p + 1) * HID + j];
    }
#pragma unroll
    for (int j = 0; j < HID; ++j) h1[j] = fmaxf(h1[j], 0.0f);

    uint4 ua, ub;
    ua.x = pack2(h1[0], h1[1]);   ua.y = pack2(h1[2], h1[3]);
    ua.z = pack2(h1[4], h1[5]);   ua.w = pack2(h1[6], h1[7]);
    ub.x = pack2(h1[8], h1[9]);   ub.y = pack2(h1[10], h1[11]);
    ub.z = pack2(h1[12], h1[13]); ub.w = (unsigned)c;
    recs[2 * (size_t)pos]     = ua;
    recs[2 * (size_t)pos + 1] = ub;
}

// K3: partition + MLP1 fused, pair-based loads: thread owns edge pairs so
// ea reads are 7 x float4 per 2 edges (3.5 VMEM instrs/edge vs 7) and ei
// reads are int2 per pair. Bucket hist in LDS as in R1 (proven 59% occ).
__global__ __launch_bounds__(256) void part_kernel(
    const float* __restrict__ x,
    const int* __restrict__ ei, int E,
    const float* __restrict__ ea,
    const float* __restrict__ w1a, const float* __restrict__ b1a,
    int* __restrict__ cursor, uint4* __restrict__ recs, int K)
{
    __shared__ int sh[MAXK];
    __shared__ int sbase[MAXK];
    __shared__ float s_w1a[15 * HID];
    __shared__ float s_b1a[HID];
    for (int i = threadIdx.x; i < 15 * HID; i += 256) s_w1a[i] = w1a[i];
    if (threadIdx.x < HID) s_b1a[threadIdx.x] = b1a[threadIdx.x];
    for (int i = threadIdx.x; i < K; i += 256) sh[i] = 0;
    __syncthreads();

    int t = threadIdx.x;
    int tile0 = blockIdx.x * PTILE;
    const int* eic = ei + E;

    // phase 1: indices + bucket ranks. 4 pairs per thread.
    int ra[4], rb[4], ca[4], cb[4], rka[4], rkb[4];
#pragma unroll
    for (int k = 0; k < 4; ++k) {
        int e0 = tile0 + 2 * (k * 256 + t);
        if (e0 + 1 < E) {
            int2 rr = *(const int2*)(ei + e0);
            int2 cc = *(const int2*)(eic + e0);
            ra[k] = rr.x; rb[k] = rr.y;
            ca[k] = cc.x; cb[k] = cc.y;
            rka[k] = atomicAdd(&sh[cc.x >> 8], 1);
            rkb[k] = atomicAdd(&sh[cc.y >> 8], 1);
        } else if (e0 < E) {                      // odd-E tail single
            ra[k] = ei[e0];
            ca[k] = eic[e0];
            rka[k] = atomicAdd(&sh[ca[k] >> 8], 1);
        }
    }
    __syncthreads();
    for (int i = t; i < K; i += 256)
        sbase[i] = sh[i] ? atomicAdd(&cursor[i], sh[i]) : 0;
    __syncthreads();

    // phase 2: MLP1 + binned record stores
#pragma unroll
    for (int k = 0; k < 4; ++k) {
        int e0 = tile0 + 2 * (k * 256 + t);
        if (e0 + 1 < E) {
            const float4* ep = (const float4*)(ea + (size_t)e0 * HID); // 112B aligned
            float4 w0 = ep[0], w1 = ep[1], w2 = ep[2], w3 = ep[3];
            float4 w4 = ep[4], w5 = ep[5], w6 = ep[6];
            float f[28] = { w0.x, w0.y, w0.z, w0.w, w1.x, w1.y, w1.z, w1.w,
                            w2.x, w2.y, w2.z, w2.w, w3.x, w3.y, w3.z, w3.w,
                            w4.x, w4.y, w4.z, w4.w, w5.x, w5.y, w5.z, w5.w,
                            w6.x, w6.y, w6.z, w6.w };
            float4 qa = ((const float4*)x)[ra[k]];
            float4 qb = ((const float4*)x)[rb[k]];
            float mna = qa.y * qa.y + qa.z * qa.z + qa.w * qa.w - qa.x * qa.x;
            float mnb = qb.y * qb.y + qb.z * qb.z + qb.w * qb.w - qb.x * qb.x;
            mlp1_store(f,      mna, s_w1a, s_b1a, ca[k],
                       sbase[ca[k] >> 8] + rka[k], recs);
            mlp1_store(f + 14, mnb, s_w1a, s_b1a, cb[k],
                       sbase[cb[k] >> 8] + rkb[k], recs);
        } else if (e0 < E) {
            float v[HID];
            const float2* ep = (const float2*)(ea + (size_t)e0 * HID);
#pragma unroll
            for (int p = 0; p < 7; ++p) {
                float2 tv = ep[p];
                v[2 * p] = tv.x;
                v[2 * p + 1] = tv.y;
            }
            float4 qa = ((const float4*)x)[ra[k]];
            float mna = qa.y * qa.y + qa.z * qa.z + qa.w * qa.w - qa.x * qa.x;
            mlp1_store(v, mna, s_w1a, s_b1a, ca[k],
                       sbase[ca[k] >> 8] + rka[k], recs);
        }
    }
}

// K4: streaming accumulate, 7 u64 LDS atomics per record.
// u64 #0: f0[0:28) + f1[28:56) (16 frac bits each) + count[56:64).
// u64 #1..6: feature pairs as 32/32 16.16 fixed.
static __device__ inline void acc_rec7(const uint4* __restrict__ recs, size_t i,
                                       unsigned long long* __restrict__ sacc,
                                       int nbase)
{
    uint4 ua = recs[2 * i];
    uint4 ub = recs[2 * i + 1];
    unsigned long long* dst = &sacc[(size_t)(((int)ub.w - nbase) * 7)];
    float2 f = unpack2(ua.x);
    unsigned long long a0 =
          (unsigned long long)(unsigned)__builtin_fmaf(f.x, 65536.0f, 0.5f)
        | ((unsigned long long)(unsigned)__builtin_fmaf(f.y, 65536.0f, 0.5f) << 28)
        | (1ULL << 56);
    atomicAdd(&dst[0], a0);
    atomicAdd(&dst[1], fx2(ua.y));
    atomicAdd(&dst[2], fx2(ua.z));
    atomicAdd(&dst[3], fx2(ua.w));
    atomicAdd(&dst[4], fx2(ub.x));
    atomicAdd(&dst[5], fx2(ub.y));
    atomicAdd(&dst[6], fx2(ub.z));
}

__global__ __launch_bounds__(256) void acc_kernel(
    const uint4* __restrict__ recs,
    const int* __restrict__ start, const int* __restrict__ hist,
    float* __restrict__ part, int N)
{
    __shared__ unsigned long long sacc[RNODE * 7];   // 14336 B
    for (int i = threadIdx.x; i < RNODE * 7; i += 256) sacc[i] = 0ULL;
    __syncthreads();

    int b = blockIdx.x / MSLICE;
    int m = blockIdx.x % MSLICE;
    int s0 = start[b], cb = hist[b];
    int lo = s0 + (int)((long long)cb * m / MSLICE);
    int hi = s0 + (int)((long long)cb * (m + 1) / MSLICE);
    int nbase = b << 8;

    int i = lo + threadIdx.x;
    for (; i < hi - 256; i += 512) {
        acc_rec7(recs, (size_t)i, sacc, nbase);
        acc_rec7(recs, (size_t)(i + 256), sacc, nbase);
    }
    if (i < hi) acc_rec7(recs, (size_t)i, sacc, nbase);
    __syncthreads();

    int t = threadIdx.x;
    int node = nbase + t;
    if (node < N) {
        const unsigned long long* p = &sacc[t * 7];
        const float sc = 1.0f / 65536.0f;
        unsigned long long p0 = p[0];
        float v[14];
        v[0] = (float)(unsigned)(p0 & 0xFFFFFFFULL) * sc;
        v[1] = (float)(unsigned)((p0 >> 28) & 0xFFFFFFFULL) * sc;
        float cnt = (float)(unsigned)(p0 >> 56);
#pragma unroll
        for (int k = 1; k < 7; ++k) {
            unsigned long long w = p[k];
            v[2 * k]     = (float)(unsigned)w         * sc;
            v[2 * k + 1] = (float)(unsigned)(w >> 32) * sc;
        }
        float4* q = (float4*)(part + ((size_t)m * N + node) * 16);
        float4 o;
        o.x = v[0];  o.y = v[1];  o.z = v[2];  o.w = v[3];  q[0] = o;
        o.x = v[4];  o.y = v[5];  o.z = v[6];  o.w = v[7];  q[1] = o;
        o.x = v[8];  o.y = v[9];  o.z = v[10]; o.w = v[11]; q[2] = o;
        o.x = v[12]; o.y = v[13]; o.z = cnt;   o.w = 0.0f;  q[3] = o;
    }
}

// K5: merge partials, mean, fold W1b/b1b (linearity), MLP2 -> out
__global__ __launch_bounds__(256) void node2_kernel(
    const float* __restrict__ x,
    const float* __restrict__ part,
    const float* __restrict__ w1b, const float* __restrict__ b1b,
    const float* __restrict__ w2a, const float* __restrict__ b2a,
    const float* __restrict__ w2b, const float* __restrict__ b2b,
    float* __restrict__ out, int N)
{
    __shared__ float s_w1b[HID * HID], s_b1b[HID];
    __shared__ float s_w2a[15 * HID], s_b2a[HID];
    __shared__ float s_w2b[HID * HID], s_b2b[HID];
    for (int i = threadIdx.x; i < HID * HID; i += 256) {
        s_w1b[i] = w1b[i];
        s_w2b[i] = w2b[i];
    }
    for (int i = threadIdx.x; i < 15 * HID; i += 256) s_w2a[i] = w2a[i];
    if (threadIdx.x < HID) {
        s_b1b[threadIdx.x] = b1b[threadIdx.x];
        s_b2a[threadIdx.x] = b2a[threadIdx.x];
        s_b2b[threadIdx.x] = b2b[threadIdx.x];
    }
    __syncthreads();

    int n = blockIdx.x * 256 + threadIdx.x;
    if (n >= N) return;

    float s[15];
    {
        const float4* p = (const float4*)(part + (size_t)n * 16);
        float4 a = p[0], bq = p[1], cq = p[2], dq = p[3];
        s[0] = a.x;  s[1] = a.y;  s[2] = a.z;  s[3] = a.w;
        s[4] = bq.x; s[5] = bq.y; s[6] = bq.z; s[7] = bq.w;
        s[8] = cq.x; s[9] = cq.y; s[10] = cq.z; s[11] = cq.w;
        s[12] = dq.x; s[13] = dq.y; s[14] = dq.z;
    }
#pragma unroll
    for (int m = 1; m < MSLICE; ++m) {
        const float4* p = (const float4*)(part + ((size_t)m * N + n) * 16);
        float4 a = p[0], bq = p[1], cq = p[2], dq = p[3];
        s[0] += a.x;  s[1] += a.y;  s[2] += a.z;  s[3] += a.w;
        s[4] += bq.x; s[5] += bq.y; s[6] += bq.z; s[7] += bq.w;
        s[8] += cq.x; s[9] += cq.y; s[10] += cq.z; s[11] += cq.w;
        s[12] += dq.x; s[13] += dq.y; s[14] += dq.z;
    }

    float cntf = s[14];
    float gate = (cntf >= 0.5f) ? 1.0f : 0.0f;
    float inv = gate / fmaxf(cntf, 1.0f);

    float mh[HID];
#pragma unroll
    for (int j = 0; j < HID; ++j) mh[j] = gate * s_b1b[j];
#pragma unroll
    for (int k = 0; k < HID; ++k) {
        float rk = s[k] * inv;
#pragma unroll
        for (int j = 0; j < HID; ++j) mh[j] += rk * s_w1b[k * HID + j];
    }

    float4 xv = ((const float4*)x)[n];
    float mn = xv.y * xv.y + xv.z * xv.z + xv.w * xv.w - xv.x * xv.x;

    float h1[HID];
#pragma unroll
    for (int j = 0; j < HID; ++j) h1[j] = s_b2a[j] + mn * s_w2a[j];
#pragma unroll
    for (int k = 0; k < HID; ++k) {
        float vk = mh[k];
#pragma unroll
        for (int j = 0; j < HID; ++j) h1[j] += vk * s_w2a[(k + 1) * HID + j];
    }
#pragma unroll
    for (int j = 0; j < HID; ++j) h1[j] = fmaxf(h1[j], 0.0f);

    float h2[HID];
#pragma unroll
    for (int j = 0; j < HID; ++j) h2[j] = s_b2b[j];
#pragma unroll
    for (int k = 0; k < HID; ++k) {
        float hk = h1[k];
#pragma unroll
        for (int j = 0; j < HID; ++j) h2[j] += hk * s_w2b[k * HID + j];
    }

    float2* op = (float2*)(out + (size_t)n * HID);
#pragma unroll
    for (int k = 0; k < 7; ++k) {
        float2 t; t.x = h2[2 * k]; t.y = h2[2 * k + 1];
        op[k] = t;
    }
}

// ============ Fallback A: edge-id bins + MLP in acc ============

__global__ __launch_bounds__(256) void r2_part_kernel(
    const int* __restrict__ ei, int E,
    int* __restrict__ cursor, int4* __restrict__ bins, int K)
{
    __shared__ int sh[MAXK];
    __shared__ int sbase[MAXK];
    for (int i = threadIdx.x; i < K; i += 256) sh[i] = 0;
    __syncthreads();
    int tile0 = blockIdx.x * PTILE;
    int e[8], r[8], c[8], rk[8];
#pragma unroll
    for (int k = 0; k < 8; ++k) {
        int idx = tile0 + k * 256 + threadIdx.x;
        e[k] = idx;
        if (idx < E) {
            r[k] = ei[idx];
            c[k] = ei[E + idx];
            rk[k] = atomicAdd(&sh[c[k] >> 8], 1);
        }
    }
    __syncthreads();
    for (int i = threadIdx.x; i < K; i += 256)
        sbase[i] = sh[i] ? atomicAdd(&cursor[i], sh[i]) : 0;
    __syncthreads();
#pragma unroll
    for (int k = 0; k < 8; ++k) {
        if (e[k] < E) {
            int pos = sbase[c[k] >> 8] + rk[k];
            int4 t; t.x = e[k]; t.y = r[k]; t.z = c[k]; t.w = 0;
            bins[pos] = t;
        }
    }
}

__global__ __launch_bounds__(256) void r2_acc_kernel(
    const float* __restrict__ x, const float* __restrict__ ea,
    const int4* __restrict__ bins,
    const int* __restrict__ start, const int* __restrict__ hist,
    const float* __restrict__ w1a, const float* __restrict__ b1a,
    const float* __restrict__ w1b, const float* __restrict__ b1b,
    float* __restrict__ part, int N)
{
    __shared__ float sacc[RNODE * 15];
    __shared__ float s_w1a[15 * HID], s_b1a[HID];
    __shared__ float s_w1b[HID * HID], s_b1b[HID];
    for (int i = threadIdx.x; i < 15 * HID; i += 256) s_w1a[i] = w1a[i];
    for (int i = threadIdx.x; i < HID * HID; i += 256) s_w1b[i] = w1b[i];
    if (threadIdx.x < HID) { s_b1a[threadIdx.x] = b1a[threadIdx.x]; s_b1b[threadIdx.x] = b1b[threadIdx.x]; }
    for (int i = threadIdx.x; i < RNODE * 15; i += 256) sacc[i] = 0.0f;
    __syncthreads();

    int b = blockIdx.x / 2, m = blockIdx.x % 2;
    int s0 = start[b], cb = hist[b];
    int lo = s0 + (int)((long long)cb * m / 2);
    int hi = s0 + (int)((long long)cb * (m + 1) / 2);
    int nbase = b << 8;

    for (int i = lo + threadIdx.x; i < hi; i += 256) {
        int4 t = bins[i];
        float4 xv = ((const float4*)x)[t.y];
        float mn = xv.y * xv.y + xv.z * xv.z + xv.w * xv.w - xv.x * xv.x;
        float v[HID];
        const float2* ep = (const float2*)(ea + (size_t)t.x * HID);
#pragma unroll
        for (int k = 0; k < 7; ++k) { float2 u2 = ep[k]; v[2*k] = u2.x; v[2*k+1] = u2.y; }
        float h1[HID];
#pragma unroll
        for (int j = 0; j < HID; ++j) h1[j] = s_b1a[j] + mn * s_w1a[j];
#pragma unroll
        for (int k = 0; k < HID; ++k) {
            float vk = v[k];
#pragma unroll
            for (int j = 0; j < HID; ++j) h1[j] += vk * s_w1a[(k + 1) * HID + j];
        }
#pragma unroll
        for (int j = 0; j < HID; ++j) h1[j] = fmaxf(h1[j], 0.0f);
        float h2[HID];
#pragma unroll
        for (int j = 0; j < HID; ++j) h2[j] = s_b1b[j];
#pragma unroll
        for (int k = 0; k < HID; ++k) {
            float hk = h1[k];
#pragma unroll
            for (int j = 0; j < HID; ++j) h2[j] += hk * s_w1b[k * HID + j];
        }
        float* dst = &sacc[(t.z - nbase) * 15];
#pragma unroll
        for (int j = 0; j < HID; ++j) atomicAdd(dst + j, h2[j]);
        atomicAdd(dst + HID, 1.0f);
    }
    __syncthreads();
    for (int i = threadIdx.x; i < RNODE * 15; i += 256) {
        int node = nbase + i / 15;
        if (node < N) part[((size_t)m * N + node) * 15 + (i % 15)] = sacc[i];
    }
}

__global__ __launch_bounds__(256) void r2_node2_kernel(
    const float* __restrict__ x, const float* __restrict__ part,
    const float* __restrict__ w2a, const float* __restrict__ b2a,
    const float* __restrict__ w2b, const float* __restrict__ b2b,
    float* __restrict__ out, int N)
{
    __shared__ float s_w2a[15 * HID], s_b2a[HID];
    __shared__ float s_w2b[HID * HID], s_b2b[HID];
    for (int i = threadIdx.x; i < 15 * HID; i += 256) s_w2a[i] = w2a[i];
    for (int i = threadIdx.x; i < HID * HID; i += 256) s_w2b[i] = w2b[i];
    if (threadIdx.x < HID) { s_b2a[threadIdx.x] = b2a[threadIdx.x]; s_b2b[threadIdx.x] = b2b[threadIdx.x]; }
    __syncthreads();
    int n = blockIdx.x * 256 + threadIdx.x;
    if (n >= N) return;
    float4 xv = ((const float4*)x)[n];
    float mn = xv.y * xv.y + xv.z * xv.z + xv.w * xv.w - xv.x * xv.x;
    float s[15];
#pragma unroll
    for (int j = 0; j < 15; ++j)
        s[j] = part[(size_t)n * 15 + j] + part[((size_t)N + n) * 15 + j];
    float inv = 1.0f / fmaxf(s[HID], 1.0f);
    float h1[HID];
#pragma unroll
    for (int j = 0; j < HID; ++j) h1[j] = s_b2a[j] + mn * s_w2a[j];
#pragma unroll
    for (int k = 0; k < HID; ++k) {
        float vk = s[k] * inv;
#pragma unroll
        for (int j = 0; j < HID; ++j) h1[j] += vk * s_w2a[(k + 1) * HID + j];
    }
#pragma unroll
    for (int j = 0; j < HID; ++j) h1[j] = fmaxf(h1[j], 0.0f);
    float h2[HID];
#pragma unroll
    for (int j = 0; j < HID; ++j) h2[j] = s_b2b[j];
#pragma unroll
    for (int k = 0; k < HID; ++k) {
        float hk = h1[k];
#pragma unroll
        for (int j = 0; j < HID; ++j) h2[j] += hk * s_w2b[k * HID + j];
    }
    float2* op = (float2*)(out + (size_t)n * HID);
#pragma unroll
    for (int k = 0; k < 7; ++k) { float2 t; t.x = h2[2*k]; t.y = h2[2*k+1]; op[k] = t; }
}

// ============ Fallback B: global atomics ============

__global__ __launch_bounds__(256) void edge_kernel(
    const float* __restrict__ x, const int* __restrict__ ei,
    const float* __restrict__ ea,
    const float* __restrict__ w1a, const float* __restrict__ b1a,
    const float* __restrict__ w1b, const float* __restrict__ b1b,
    float* __restrict__ seg, float* __restrict__ cnt, int E)
{
    __shared__ float s_w1a[15 * HID], s_b1a[HID];
    __shared__ float s_w1b[HID * HID], s_b1b[HID];
    for (int i = threadIdx.x; i < 15 * HID; i += 256) s_w1a[i] = w1a[i];
    for (int i = threadIdx.x; i < HID * HID; i += 256) s_w1b[i] = w1b[i];
    if (threadIdx.x < HID) { s_b1a[threadIdx.x] = b1a[threadIdx.x]; s_b1b[threadIdx.x] = b1b[threadIdx.x]; }
    __syncthreads();
    int e = blockIdx.x * 256 + threadIdx.x;
    if (e >= E) return;
    int r = ei[e], c = ei[E + e];
    float4 xv = ((const float4*)x)[r];
    float mn = xv.y * xv.y + xv.z * xv.z + xv.w * xv.w - xv.x * xv.x;
    float v[HID];
    const float2* ep = (const float2*)(ea + (size_t)e * HID);
#pragma unroll
    for (int k = 0; k < 7; ++k) { float2 t = ep[k]; v[2*k] = t.x; v[2*k+1] = t.y; }
    float h1[HID];
#pragma unroll
    for (int j = 0; j < HID; ++j) h1[j] = s_b1a[j] + mn * s_w1a[j];
#pragma unroll
    for (int k = 0; k < HID; ++k) {
        float vk = v[k];
#pragma unroll
        for (int j = 0; j < HID; ++j) h1[j] += vk * s_w1a[(k + 1) * HID + j];
    }
#pragma unroll
    for (int j = 0; j < HID; ++j) h1[j] = fmaxf(h1[j], 0.0f);
    float h2[HID];
#pragma unroll
    for (int j = 0; j < HID; ++j) h2[j] = s_b1b[j];
#pragma unroll
    for (int k = 0; k < HID; ++k) {
        float hk = h1[k];
#pragma unroll
        for (int j = 0; j < HID; ++j) h2[j] += hk * s_w1b[k * HID + j];
    }
    float* dst = seg + (size_t)c * HID;
#pragma unroll
    for (int j = 0; j < HID; ++j) unsafeAtomicAdd(dst + j, h2[j]);
    unsafeAtomicAdd(cnt + c, 1.0f);
}

__global__ __launch_bounds__(256) void node_kernel(
    const float* __restrict__ x, const float* __restrict__ seg,
    const float* __restrict__ cnt,
    const float* __restrict__ w2a, const float* __restrict__ b2a,
    const float* __restrict__ w2b, const float* __restrict__ b2b,
    float* __restrict__ out, int N)
{
    __shared__ float s_w2a[15 * HID], s_b2a[HID];
    __shared__ float s_w2b[HID * HID], s_b2b[HID];
    for (int i = threadIdx.x; i < 15 * HID; i += 256) s_w2a[i] = w2a[i];
    for (int i = threadIdx.x; i < HID * HID; i += 256) s_w2b[i] = w2b[i];
    if (threadIdx.x < HID) { s_b2a[threadIdx.x] = b2a[threadIdx.x]; s_b2b[threadIdx.x] = b2b[threadIdx.x]; }
    __syncthreads();
    int n = blockIdx.x * 256 + threadIdx.x;
    if (n >= N) return;
    float4 xv = ((const float4*)x)[n];
    float mn = xv.y * xv.y + xv.z * xv.z + xv.w * xv.w - xv.x * xv.x;
    float inv = 1.0f / fmaxf(cnt[n], 1.0f);
    float v[HID];
    const float2* sp = (const float2*)(seg + (size_t)n * HID);
#pragma unroll
    for (int k = 0; k < 7; ++k) { float2 t = sp[k]; v[2*k] = t.x*inv; v[2*k+1] = t.y*inv; }
    float h1[HID];
#pragma unroll
    for (int j = 0; j < HID; ++j) h1[j] = s_b2a[j] + mn * s_w2a[j];
#pragma unroll
    for (int k = 0; k < HID; ++k) {
        float vk = v[k];
#pragma unroll
        for (int j = 0; j < HID; ++j) h1[j] += vk * s_w2a[(k + 1) * HID + j];
    }
#pragma unroll
    for (int j = 0; j < HID; ++j) h1[j] = fmaxf(h1[j], 0.0f);
    float h2[HID];
#pragma unroll
    for (int j = 0; j < HID; ++j) h2[j] = s_b2b[j];
#pragma unroll
    for (int k = 0; k < HID; ++k) {
        float hk = h1[k];
#pragma unroll
        for (int j = 0; j < HID; ++j) h2[j] += hk * s_w2b[k * HID + j];
    }
    float2* op = (float2*)(out + (size_t)n * HID);
#pragma unroll
    for (int k = 0; k < 7; ++k) { float2 t; t.x = h2[2*k]; t.y = h2[2*k+1]; op[k] = t; }
}

// ============ Launch ============

extern "C" void kernel_launch(void* const* d_in, const int* in_sizes, int n_in,
                              void* d_out, int out_size, void* d_ws, size_t ws_size,
                              hipStream_t stream)
{
    const float* x   = (const float*)d_in[0];
    const int*   ei  = (const int*)d_in[1];
    const float* ea  = (const float*)d_in[2];
    const float* w1a = (const float*)d_in[5];
    const float* b1a = (const float*)d_in[6];
    const float* w1b = (const float*)d_in[7];
    const float* b1b = (const float*)d_in[8];
    const float* w2a = (const float*)d_in[9];
    const float* b2a = (const float*)d_in[10];
    const float* w2b = (const float*)d_in[11];
    const float* b2b = (const float*)d_in[12];

    const int N = in_sizes[0] / 4;   // 100000
    const int E = in_sizes[1] / 2;   // 6400000
    const int K = (N + RNODE - 1) / RNODE;

    size_t recs_bytes = (size_t)E * 32;
    size_t part_bytes = (size_t)MSLICE * N * 16 * sizeof(float);
    size_t ints_bytes = (size_t)3 * MAXK * sizeof(int);
    size_t need_fast = recs_bytes + part_bytes + ints_bytes + 256;

    size_t bins_bytes = (size_t)E * sizeof(int4);
    size_t r2part_bytes = (size_t)2 * N * 15 * sizeof(float);
    size_t need_r2 = bins_bytes + r2part_bytes + ints_bytes + 256;

    if (K <= MAXK && ws_size >= need_fast) {
        uint4* recs   = (uint4*)d_ws;
        float* part   = (float*)((char*)d_ws + recs_bytes);
        int*   hist   = (int*)((char*)d_ws + recs_bytes + part_bytes);
        int*   cursor = hist + MAXK;
        int*   start  = cursor + MAXK;

        hipMemsetAsync(hist, 0, (size_t)K * sizeof(int), stream);
        hist_kernel<<<1024, 256, 0, stream>>>(ei + E, E, hist, K);
        scan_kernel<<<1, 512, 0, stream>>>(hist, start, cursor, K);
        int pb = (E + PTILE - 1) / PTILE;
        part_kernel<<<pb, 256, 0, stream>>>(x, ei, E, ea, w1a, b1a, cursor, recs, K);
        acc_kernel<<<K * MSLICE, 256, 0, stream>>>(recs, start, hist, part, N);
        int nb = (N + 255) / 256;
        node2_kernel<<<nb, 256, 0, stream>>>(x, part, w1b, b1b, w2a, b2a, w2b, b2b,
                                             (float*)d_out, N);
    } else if (K <= MAXK && ws_size >= need_r2) {
        int4*  bins   = (int4*)d_ws;
        float* part   = (float*)((char*)d_ws + bins_bytes);
        int*   hist   = (int*)((char*)d_ws + bins_bytes + r2part_bytes);
        int*   cursor = hist + MAXK;
        int*   start  = cursor + MAXK;

        hipMemsetAsync(hist, 0, (size_t)K * sizeof(int), stream);
        hist_kernel<<<1024, 256, 0, stream>>>(ei + E, E, hist, K);
        scan_kernel<<<1, 512, 0, stream>>>(hist, start, cursor, K);
        int pb = (E + PTILE - 1) / PTILE;
        r2_part_kernel<<<pb, 256, 0, stream>>>(ei, E, cursor, bins, K);
        r2_acc_kernel<<<K * 2, 256, 0, stream>>>(x, ea, bins, start, hist,
                                                 w1a, b1a, w1b, b1b, part, N);
        int nb = (N + 255) / 256;
        r2_node2_kernel<<<nb, 256, 0, stream>>>(x, part, w2a, b2a, w2b, b2b,
                                                (float*)d_out, N);
    } else {
        float* seg = (float*)d_ws;
        float* cnt = seg + (size_t)N * HID;
        hipMemsetAsync(d_ws, 0, (size_t)N * (HID + 1) * sizeof(float), stream);
        int eb = (E + 255) / 256;
        edge_kernel<<<eb, 256, 0, stream>>>(x, ei, ea, w1a, b1a, w1b, b1b, seg, cnt, E);
        int nb = (N + 255) / 256;
        node_kernel<<<nb, 256, 0, stream>>>(x, seg, cnt, w2a, b2a, w2b, b2b,
                                            (float*)d_out, N);
    }
}